// Round 7
// baseline (246.407 us; speedup 1.0000x reference)
//
#include <hip/hip_runtime.h>

#define TIME_STEP 8
#define VTH 1.0f
#define TAU 0.5f

typedef float floatx4 __attribute__((ext_vector_type(4)));

// Round-4 post-mortem: compiler register-minimized (VGPR=24) -> only ONE
// outstanding load per thread -> latency-bound at 2.2 TB/s. This version
// forces all 8 time-slice loads in flight BEFORE the recurrence:
//   - unrolled load loop into a register array (static indices -> VGPRs)
//   - sched_barrier(0) pins loads above the compute (compiler may not sink)
// Then the recurrence is a pure-VALU chain and 8 NT stores stream out.
__global__ __launch_bounds__(256) void lif_kernel(const floatx4* __restrict__ x,
                                                  floatx4* __restrict__ o,
                                                  int n4) {
    const int i = blockIdx.x * blockDim.x + threadIdx.x;
    if (i >= n4) return;

    floatx4 xt[TIME_STEP];
#pragma unroll
    for (int t = 0; t < TIME_STEP; ++t) {
        xt[t] = x[(size_t)t * n4 + i];           // 8 independent loads, 32 VGPRs
    }
    __builtin_amdgcn_sched_barrier(0);           // keep all 8 loads issued first

    float ux = 0.f, uy = 0.f, uz = 0.f, uw = 0.f;
#pragma unroll
    for (int t = 0; t < TIME_STEP; ++t) {
        // u_new = tau*u*(1-spike(u)) + x_t  ==  (u>VTH ? 0 : tau*u) + x_t
        ux = (ux > VTH ? 0.f : TAU * ux) + xt[t].x;
        uy = (uy > VTH ? 0.f : TAU * uy) + xt[t].y;
        uz = (uz > VTH ? 0.f : TAU * uz) + xt[t].z;
        uw = (uw > VTH ? 0.f : TAU * uw) + xt[t].w;
        floatx4 ot;
        ot.x = ux > VTH ? 1.f : 0.f;
        ot.y = uy > VTH ? 1.f : 0.f;
        ot.z = uz > VTH ? 1.f : 0.f;
        ot.w = uw > VTH ? 1.f : 0.f;
        __builtin_nontemporal_store(ot, &o[(size_t)t * n4 + i]);
    }
}

extern "C" void kernel_launch(void* const* d_in, const int* in_sizes, int n_in,
                              void* d_out, int out_size, void* d_ws, size_t ws_size,
                              hipStream_t stream) {
    const floatx4* x = (const floatx4*)d_in[0];
    floatx4* o = (floatx4*)d_out;
    const int n4 = in_sizes[0] / (TIME_STEP * 4);   // float4s per time slice
    const int block = 256;
    const int grid = (n4 + block - 1) / block;      // flat grid, one iter/thread
    lif_kernel<<<grid, block, 0, stream>>>(x, o, n4);
}

// Round 11
// 241.570 us; speedup vs baseline: 1.0200x; 1.0200x over previous
//
#include <hip/hip_runtime.h>

#define TIME_STEP 8
#define VTH 1.0f
#define TAU 0.5f

typedef float floatx4 __attribute__((ext_vector_type(4)));

// Round-7 post-mortem: sched_barrier(0) did NOT stop IR-level load sinking
// (VGPR fell to 20 -> serial load->wait->compute->store chain, latency-bound
// at 2.1 TB/s). This version pins the 8 loads with an asm USE of all loaded
// values: the loads cannot sink past an instruction that consumes them, so
// all 8 global_load_dwordx4 are in flight together (8 KB/wave in flight).
// Stores are batched at the end so no per-iteration vmcnt(0) couples the
// recurrence to store-acks.
__global__ __launch_bounds__(256) void lif_kernel(const floatx4* __restrict__ x,
                                                  floatx4* __restrict__ o,
                                                  int n4) {
    const int i = blockIdx.x * blockDim.x + threadIdx.x;
    if (i >= n4) return;

    floatx4 x0 = x[(size_t)0 * n4 + i];
    floatx4 x1 = x[(size_t)1 * n4 + i];
    floatx4 x2 = x[(size_t)2 * n4 + i];
    floatx4 x3 = x[(size_t)3 * n4 + i];
    floatx4 x4 = x[(size_t)4 * n4 + i];
    floatx4 x5 = x[(size_t)5 * n4 + i];
    floatx4 x6 = x[(size_t)6 * n4 + i];
    floatx4 x7 = x[(size_t)7 * n4 + i];
    // Force all 8 loaded values live here: loads must issue before this point
    // and cannot be sunk to their uses (defeats register-minimization).
    asm volatile("" :: "v"(x0), "v"(x1), "v"(x2), "v"(x3),
                       "v"(x4), "v"(x5), "v"(x6), "v"(x7));

    floatx4 u = {0.f, 0.f, 0.f, 0.f};
    floatx4 ot[TIME_STEP];
    const floatx4 xt[TIME_STEP] = {x0, x1, x2, x3, x4, x5, x6, x7};
#pragma unroll
    for (int t = 0; t < TIME_STEP; ++t) {
        // u_new = tau*u*(1-spike(u)) + x_t  ==  (u>VTH ? 0 : tau*u) + x_t
        u.x = (u.x > VTH ? 0.f : TAU * u.x) + xt[t].x;
        u.y = (u.y > VTH ? 0.f : TAU * u.y) + xt[t].y;
        u.z = (u.z > VTH ? 0.f : TAU * u.z) + xt[t].z;
        u.w = (u.w > VTH ? 0.f : TAU * u.w) + xt[t].w;
        ot[t].x = u.x > VTH ? 1.f : 0.f;
        ot[t].y = u.y > VTH ? 1.f : 0.f;
        ot[t].z = u.z > VTH ? 1.f : 0.f;
        ot[t].w = u.w > VTH ? 1.f : 0.f;
    }
#pragma unroll
    for (int t = 0; t < TIME_STEP; ++t) {
        __builtin_nontemporal_store(ot[t], &o[(size_t)t * n4 + i]);
    }
}

extern "C" void kernel_launch(void* const* d_in, const int* in_sizes, int n_in,
                              void* d_out, int out_size, void* d_ws, size_t ws_size,
                              hipStream_t stream) {
    const floatx4* x = (const floatx4*)d_in[0];
    floatx4* o = (floatx4*)d_out;
    const int n4 = in_sizes[0] / (TIME_STEP * 4);   // float4s per time slice
    const int block = 256;
    const int grid = (n4 + block - 1) / block;      // flat grid, one iter/thread
    lif_kernel<<<grid, block, 0, stream>>>(x, o, n4);
}